// Round 2
// baseline (238.947 us; speedup 1.0000x reference)
//
#include <hip/hip_runtime.h>

// SimpleDialogGNN on MI355X — round 2.
// Key identity: msg@W_msg == window(x)@W_msg == window(x@W_msg).
// Pipeline:
//   K0 pack_x        : x fp32 -> xbf bf16 (8192x1024)
//   K1 transpose_pack: W_self,W_msg -> wt1 (N=2048 x K=1024 bf16, N-major)
//                      W_out        -> wt_out (1024x1024 bf16, N-major)
//   K2 gemm<1024,0>  : [u|v] = xbf @ wt1^T   grid 16x64 = 1024 blocks (4/CU)
//   K3 combine       : h = u + window(v) + b_self + b_msg; out = sel(h,x);
//                      r = relu(out) -> bf16
//   K4 gemm<512,1>   : split-K=2: P0,P1 = r @ wt_out^T partials (bf16)
//                      grid 8x64x2 = 1024 blocks (4/CU)
//   K5 ln_final      : z = x + P0 + P1 + b_out; LayerNorm -> d_out
//
// ws aliasing (54 MiB total):
//   region0 [ 0,16M): xbf  -> r   (xbf dead after K2)
//   region1 [16,32M): u    -> P0  (u dead after K3)
//   region2 [32,48M): v    -> P1  (v dead after K3)
//   [48,52M): wt1   [52,54M): wt_out

typedef unsigned short u16;
typedef float floatx4 __attribute__((ext_vector_type(4)));
typedef short shortx8 __attribute__((ext_vector_type(8)));

#define T_ 1024
#define H_ 1024

__device__ __forceinline__ float bf2f(u16 v) {
    return __uint_as_float(((unsigned)v) << 16);
}
__device__ __forceinline__ u16 f2bf(float f) {  // round-to-nearest-even
    unsigned u = __float_as_uint(f);
    return (u16)((u + 0x7fffu + ((u >> 16) & 1u)) >> 16);
}
__device__ __forceinline__ void async16(const void* g, void* l) {
    __builtin_amdgcn_global_load_lds(
        (__attribute__((address_space(1))) void*)g,
        (__attribute__((address_space(3))) void*)l, 16, 0, 0);
}

// ---------------- K0: x fp32 -> bf16 ----------------------------------------
__global__ __launch_bounds__(256)
void pack_x(const float* __restrict__ x, u16* __restrict__ xbf)
{
    const size_t i = ((size_t)blockIdx.x * 256 + threadIdx.x) * 4;
    float4 v = *(const float4*)(x + i);
    ushort4 o;
    o.x = f2bf(v.x); o.y = f2bf(v.y); o.z = f2bf(v.z); o.w = f2bf(v.w);
    *(ushort4*)(xbf + i) = o;
}

// ---------------- K1: transpose + fp32->bf16 pack of the three weights ------
__global__ __launch_bounds__(256)
void transpose_pack(const float* __restrict__ Wself, const float* __restrict__ Wmsg,
                    const float* __restrict__ Wout,
                    u16* __restrict__ wt1, u16* __restrict__ wt_out)
{
    __shared__ float s[32][33];
    const int wid = blockIdx.z;
    const float* src = (wid == 0) ? Wself : ((wid == 1) ? Wmsg : Wout);
    const int n0 = blockIdx.x * 32, k0 = blockIdx.y * 32;
    const int tx = threadIdx.x & 31, ty = threadIdx.x >> 5;  // 32x8
#pragma unroll
    for (int i = 0; i < 4; ++i) {
        int k = k0 + ty + 8 * i;
        s[ty + 8 * i][tx] = src[(size_t)k * H_ + n0 + tx];
    }
    __syncthreads();
#pragma unroll
    for (int i = 0; i < 4; ++i) {
        int n = n0 + ty + 8 * i;
        u16 v = f2bf(s[tx][ty + 8 * i]);
        if (wid == 0)      wt1[(size_t)n * 1024 + k0 + tx] = v;
        else if (wid == 1) wt1[(size_t)(n + 1024) * 1024 + k0 + tx] = v;
        else               wt_out[(size_t)n * 1024 + k0 + tx] = v;
    }
}

// ---------------- K2/K4: bf16 MFMA GEMM (m97 structure) ----------------------
// A: M x 1024 row-major bf16; Bt: N x 1024 row-major bf16 (N-major).
// 128x128 tile, BK=32, 4 waves each computing 64x64 via 4x4 mfma 16x16x32.
// KLEN: K span per block (k-base = blockIdx.z * KLEN).
// EPI 0: cols [0,1024) -> O0, [1024,2048) -> O1 (u|v split)
// EPI 1: write bf16 partial to (blockIdx.z ? O1 : O0)
template <int KLEN, int EPI>
__global__ __launch_bounds__(256)
void gemm_bt(const u16* __restrict__ A, const u16* __restrict__ Bt,
             u16* __restrict__ O0, u16* __restrict__ O1)
{
    __shared__ u16 sA[128 * 32];  // 8 KiB
    __shared__ u16 sB[128 * 32];  // 8 KiB
    const int tid = threadIdx.x;
    const int bn = blockIdx.x * 128;
    const int bm = blockIdx.y * 128;
    const int kb = blockIdx.z * KLEN;
    const int wave = tid >> 6, lane = tid & 63;
    const int wr = wave >> 1, wc = wave & 1;
    const int lrow = lane & 15, lq = lane >> 4;

    const u16* gA0 = A + (size_t)(bm + (tid >> 2)) * 1024 + kb + (tid & 3) * 8;
    const u16* gA1 = gA0 + (size_t)64 * 1024;
    const u16* gB0 = Bt + (size_t)(bn + (tid >> 2)) * 1024 + kb + (tid & 3) * 8;
    const u16* gB1 = gB0 + (size_t)64 * 1024;
    u16* lA = sA + wave * 512;  // wave-uniform base; lane scatter = lane*16B
    u16* lB = sB + wave * 512;

    floatx4 acc[4][4];
#pragma unroll
    for (int i = 0; i < 4; ++i)
#pragma unroll
        for (int j = 0; j < 4; ++j)
            acc[i][j] = (floatx4){0.f, 0.f, 0.f, 0.f};

    const u16* pa = sA + (wr * 64 + lrow) * 32 + lq * 8;
    const u16* pb = sB + (wc * 64 + lrow) * 32 + lq * 8;

    for (int k0 = 0; k0 < KLEN; k0 += 32) {
        __syncthreads();
        async16(gA0 + k0, lA);
        async16(gA1 + k0, lA + 2048);
        async16(gB0 + k0, lB);
        async16(gB1 + k0, lB + 2048);
        __syncthreads();
        shortx8 av[4], bv[4];
#pragma unroll
        for (int i = 0; i < 4; ++i) av[i] = *(const shortx8*)(pa + i * 512);
#pragma unroll
        for (int j = 0; j < 4; ++j) bv[j] = *(const shortx8*)(pb + j * 512);
#pragma unroll
        for (int i = 0; i < 4; ++i)
#pragma unroll
            for (int j = 0; j < 4; ++j)
                acc[i][j] = __builtin_amdgcn_mfma_f32_16x16x32_bf16(
                    av[i], bv[j], acc[i][j], 0, 0, 0);
    }

    // epilogue — C/D mapping: col = lane&15, row = (lane>>4)*4 + reg
    u16* O;
    int cbase;
    if (EPI == 0) { O = (bn < 1024) ? O0 : O1; cbase = bn & 1023; }
    else          { O = blockIdx.z ? O1 : O0;  cbase = bn; }
#pragma unroll
    for (int i = 0; i < 4; ++i) {
        const int row0 = bm + wr * 64 + i * 16 + lq * 4;
#pragma unroll
        for (int j = 0; j < 4; ++j) {
            const int col = cbase + wc * 64 + j * 16 + lrow;
#pragma unroll
            for (int r = 0; r < 4; ++r)
                O[(size_t)(row0 + r) * 1024 + col] = f2bf(acc[i][j][r]);
        }
    }
}

// ---------------- K3: combine = u + window(v) + biases, select, relu --------
__global__ __launch_bounds__(256)
void combine(const u16* __restrict__ u, const u16* __restrict__ v,
             const float* __restrict__ x, const float* __restrict__ qmask,
             const int* __restrict__ dia_len, const float* __restrict__ b_self,
             const float* __restrict__ b_msg, u16* __restrict__ r)
{
    __shared__ u16 sv[32][1024];  // 64 KiB
    const int tid = threadIdx.x;
    const int b = blockIdx.y;
    const int t0 = blockIdx.x * 16;
    const int dlen = dia_len[b];
    const int c4 = tid * 4;

    unsigned spkmask = 0;
#pragma unroll 4
    for (int rr = 0; rr < 32; ++rr) {
        int row = t0 - 8 + rr;
        row = row < 0 ? 0 : (row > T_ - 1 ? T_ - 1 : row);
        const float* q = qmask + ((size_t)b * T_ + row) * 2;
        spkmask |= (q[1] > q[0] ? 1u : 0u) << rr;
        *(ushort4*)&sv[rr][c4] =
            *(const ushort4*)(v + ((size_t)b * T_ + row) * 1024 + c4);
    }
    __syncthreads();

    float4 bs;
    {
        float4 b1 = *(const float4*)(b_self + c4);
        float4 b2 = *(const float4*)(b_msg + c4);
        bs.x = b1.x + b2.x; bs.y = b1.y + b2.y;
        bs.z = b1.z + b2.z; bs.w = b1.w + b2.w;
    }

    for (int lt = 0; lt < 16; ++lt) {
        const int t = t0 + lt;
        const unsigned cs = (spkmask >> (lt + 8)) & 1u;
        float a0 = 0.f, a1 = 0.f, a2 = 0.f, a3 = 0.f;
        int cnt = 0;
#pragma unroll
        for (int o = 0; o < 17; ++o) {
            const int idx = t + o - 8;
            if (idx >= 0 && idx < dlen) {  // block-uniform branch
                const float w = (((spkmask >> (lt + o)) & 1u) == cs) ? 1.0f : 0.5f;
                ++cnt;
                ushort4 uu = *(const ushort4*)&sv[lt + o][c4];
                a0 += w * bf2f(uu.x); a1 += w * bf2f(uu.y);
                a2 += w * bf2f(uu.z); a3 += w * bf2f(uu.w);
            }
        }
        const float inv = 1.0f / (float)(cnt > 0 ? cnt : 1);
        const size_t rowg = (size_t)b * T_ + t;
        ushort4 u4 = *(const ushort4*)(u + rowg * 1024 + c4);
        float4 xv = *(const float4*)(x + rowg * H_ + c4);
        const bool sel = (t < dlen);
        float h0 = bf2f(u4.x) + bs.x + a0 * inv;
        float h1 = bf2f(u4.y) + bs.y + a1 * inv;
        float h2 = bf2f(u4.z) + bs.z + a2 * inv;
        float h3 = bf2f(u4.w) + bs.w + a3 * inv;
        ushort4 out;
        out.x = f2bf(fmaxf(sel ? h0 : xv.x, 0.f));
        out.y = f2bf(fmaxf(sel ? h1 : xv.y, 0.f));
        out.z = f2bf(fmaxf(sel ? h2 : xv.z, 0.f));
        out.w = f2bf(fmaxf(sel ? h3 : xv.w, 0.f));
        *(ushort4*)(r + rowg * 1024 + c4) = out;
    }
}

// ---------------- K5: z = x + P0 + P1 + b_out; LayerNorm --------------------
__global__ __launch_bounds__(256)
void ln_final(const u16* __restrict__ P0, const u16* __restrict__ P1,
              const float* __restrict__ x, const float* __restrict__ b_out,
              const float* __restrict__ gamma, const float* __restrict__ beta,
              float* __restrict__ out)
{
    const int row = blockIdx.x;
    const int tid = threadIdx.x;
    const size_t base = (size_t)row * H_ + tid * 4;
    float4 xv = *(const float4*)(x + base);
    ushort4 p0 = *(const ushort4*)(P0 + base);
    ushort4 p1 = *(const ushort4*)(P1 + base);
    float4 bo = *(const float4*)(b_out + tid * 4);
    float4 v;
    v.x = xv.x + bf2f(p0.x) + bf2f(p1.x) + bo.x;
    v.y = xv.y + bf2f(p0.y) + bf2f(p1.y) + bo.y;
    v.z = xv.z + bf2f(p0.z) + bf2f(p1.z) + bo.z;
    v.w = xv.w + bf2f(p0.w) + bf2f(p1.w) + bo.w;
    float s = v.x + v.y + v.z + v.w;
    float q = v.x * v.x + v.y * v.y + v.z * v.z + v.w * v.w;
#pragma unroll
    for (int off = 32; off > 0; off >>= 1) {
        s += __shfl_down(s, off);
        q += __shfl_down(q, off);
    }
    __shared__ float ps[4], pq[4];
    const int wave = tid >> 6, lane = tid & 63;
    if (lane == 0) { ps[wave] = s; pq[wave] = q; }
    __syncthreads();
    const float S = ps[0] + ps[1] + ps[2] + ps[3];
    const float Q = pq[0] + pq[1] + pq[2] + pq[3];
    const float mean = S * (1.0f / 1024.0f);
    const float var = Q * (1.0f / 1024.0f) - mean * mean;
    const float inv = rsqrtf(var + 1e-5f);
    float4 g = *(const float4*)(gamma + tid * 4);
    float4 bt = *(const float4*)(beta + tid * 4);
    float4 o;
    o.x = g.x * (v.x - mean) * inv + bt.x;
    o.y = g.y * (v.y - mean) * inv + bt.y;
    o.z = g.z * (v.z - mean) * inv + bt.z;
    o.w = g.w * (v.w - mean) * inv + bt.w;
    *(float4*)(out + base) = o;
}

// ---------------- launcher ---------------------------------------------------
extern "C" void kernel_launch(void* const* d_in, const int* in_sizes, int n_in,
                              void* d_out, int out_size, void* d_ws, size_t ws_size,
                              hipStream_t stream)
{
    (void)in_sizes; (void)n_in; (void)out_size; (void)ws_size;
    const float* x       = (const float*)d_in[0];
    const float* qmask   = (const float*)d_in[1];
    const int*   dia_len = (const int*)d_in[2];
    const float* W_msg   = (const float*)d_in[5];
    const float* b_msg   = (const float*)d_in[6];
    const float* W_self  = (const float*)d_in[7];
    const float* b_self  = (const float*)d_in[8];
    const float* W_out   = (const float*)d_in[9];
    const float* b_out   = (const float*)d_in[10];
    const float* gamma   = (const float*)d_in[11];
    const float* beta    = (const float*)d_in[12];
    float* out = (float*)d_out;

    char* ws = (char*)d_ws;
    u16* region0 = (u16*)ws;                           // xbf -> r
    u16* region1 = (u16*)(ws + (size_t)(16u << 20));   // u   -> P0
    u16* region2 = (u16*)(ws + (size_t)(32u << 20));   // v   -> P1
    u16* wt1     = (u16*)(ws + (size_t)(48u << 20));   // 4 MiB
    u16* wt_out  = (u16*)(ws + (size_t)(52u << 20));   // 2 MiB

    pack_x<<<dim3(8192), 256, 0, stream>>>(x, region0);
    transpose_pack<<<dim3(32, 32, 3), 256, 0, stream>>>(W_self, W_msg, W_out,
                                                        wt1, wt_out);
    gemm_bt<1024, 0><<<dim3(16, 64, 1), 256, 0, stream>>>(region0, wt1,
                                                          region1, region2);
    combine<<<dim3(64, 8), 256, 0, stream>>>(region1, region2, x, qmask,
                                             dia_len, b_self, b_msg, region0);
    gemm_bt<512, 1><<<dim3(8, 64, 2), 256, 0, stream>>>(region0, wt_out,
                                                        region1, region2);
    ln_final<<<dim3(8192), 256, 0, stream>>>(region1, region2, x, b_out,
                                             gamma, beta, out);
}

// Round 3
// 234.489 us; speedup vs baseline: 1.0190x; 1.0190x over previous
//
#include <hip/hip_runtime.h>

// SimpleDialogGNN on MI355X — round 3.
// Identity: msg@W_msg == window(x@W_msg).
// Pipeline:
//   K0 pack_x        : x fp32 -> xbf bf16
//   K1 transpose_pack: W_self,W_msg -> wt1 (2048x1024 bf16 N-major); W_out -> wt_out
//   K2 gemm<1024,0>  : [u|v] = xbf @ wt1^T   (grid 16x64, dbuf LDS + raw vmcnt(4) barrier)
//   K3 combine       : r = relu(sel(u + window(v) + biases, x)) written IN-PLACE over u
//   K4 gemm<512,1>   : split-K=2 partials P0,P1 = r @ wt_out^T (grid 8x64x2)
//   K5 ln_final      : z = x + P0 + P1 + b_out; LayerNorm -> out
//
// ws aliasing (54 MiB):
//   region0 [ 0,16M): xbf  -> P1   (xbf dead after K2)
//   region1 [16,32M): u    -> r    (in-place in K3) -> GEMM2 A
//   region2 [32,48M): v    -> P0   (v dead after K3)
//   [48,52M): wt1   [52,54M): wt_out

typedef unsigned short u16;
typedef float floatx4 __attribute__((ext_vector_type(4)));
typedef short shortx8 __attribute__((ext_vector_type(8)));

#define T_ 1024
#define H_ 1024

__device__ __forceinline__ float bf2f(u16 v) {
    return __uint_as_float(((unsigned)v) << 16);
}
__device__ __forceinline__ u16 f2bf(float f) {  // round-to-nearest-even
    unsigned u = __float_as_uint(f);
    return (u16)((u + 0x7fffu + ((u >> 16) & 1u)) >> 16);
}
__device__ __forceinline__ void async16(const void* g, void* l) {
    __builtin_amdgcn_global_load_lds(
        (__attribute__((address_space(1))) void*)g,
        (__attribute__((address_space(3))) void*)l, 16, 0, 0);
}

// ---------------- K0: x fp32 -> bf16 ----------------------------------------
__global__ __launch_bounds__(256)
void pack_x(const float* __restrict__ x, u16* __restrict__ xbf)
{
    const size_t i = ((size_t)blockIdx.x * 256 + threadIdx.x) * 4;
    float4 v = *(const float4*)(x + i);
    ushort4 o;
    o.x = f2bf(v.x); o.y = f2bf(v.y); o.z = f2bf(v.z); o.w = f2bf(v.w);
    *(ushort4*)(xbf + i) = o;
}

// ---------------- K1: transpose + fp32->bf16 pack of the three weights ------
__global__ __launch_bounds__(256)
void transpose_pack(const float* __restrict__ Wself, const float* __restrict__ Wmsg,
                    const float* __restrict__ Wout,
                    u16* __restrict__ wt1, u16* __restrict__ wt_out)
{
    __shared__ float s[32][33];
    const int wid = blockIdx.z;
    const float* src = (wid == 0) ? Wself : ((wid == 1) ? Wmsg : Wout);
    const int n0 = blockIdx.x * 32, k0 = blockIdx.y * 32;
    const int tx = threadIdx.x & 31, ty = threadIdx.x >> 5;  // 32x8
#pragma unroll
    for (int i = 0; i < 4; ++i) {
        int k = k0 + ty + 8 * i;
        s[ty + 8 * i][tx] = src[(size_t)k * H_ + n0 + tx];
    }
    __syncthreads();
#pragma unroll
    for (int i = 0; i < 4; ++i) {
        int n = n0 + ty + 8 * i;
        u16 v = f2bf(s[tx][ty + 8 * i]);
        if (wid == 0)      wt1[(size_t)n * 1024 + k0 + tx] = v;
        else if (wid == 1) wt1[(size_t)(n + 1024) * 1024 + k0 + tx] = v;
        else               wt_out[(size_t)n * 1024 + k0 + tx] = v;
    }
}

// ---------------- K2/K4: bf16 MFMA GEMM, double-buffered LDS -----------------
// A: M x 1024 row-major bf16; Bt: N x 1024 row-major bf16 (N-major).
// 128x128 tile, BK=32, dbuf LDS; prefetch s+1 before raw vmcnt(4)+s_barrier
// so next-step global_load_lds stays in flight across the barrier.
// EPI 0: cols [0,1024)->O0, [1024,2048)->O1.  EPI 1: partial -> (z ? O1 : O0).
template <int KLEN, int EPI>
__global__ __launch_bounds__(256)
void gemm_bt(const u16* __restrict__ A, const u16* __restrict__ Bt,
             u16* __restrict__ O0, u16* __restrict__ O1)
{
    __shared__ u16 smem[2 * 8192];  // [buf][A 4096 u16 | B 4096 u16] = 32 KiB
    const int tid = threadIdx.x;
    const int bn = blockIdx.x * 128;
    const int bm = blockIdx.y * 128;
    const int kb = blockIdx.z * KLEN;
    const int wave = tid >> 6, lane = tid & 63;
    const int wr = wave >> 1, wc = wave & 1;
    const int lrow = lane & 15, lq = lane >> 4;

    const u16* gA0 = A + (size_t)(bm + (tid >> 2)) * 1024 + kb + (tid & 3) * 8;
    const u16* gA1 = gA0 + (size_t)64 * 1024;
    const u16* gB0 = Bt + (size_t)(bn + (tid >> 2)) * 1024 + kb + (tid & 3) * 8;
    const u16* gB1 = gB0 + (size_t)64 * 1024;

    floatx4 acc[4][4];
#pragma unroll
    for (int i = 0; i < 4; ++i)
#pragma unroll
        for (int j = 0; j < 4; ++j)
            acc[i][j] = (floatx4){0.f, 0.f, 0.f, 0.f};

    const int aoff = (wr * 64 + lrow) * 32 + lq * 8;
    const int boff = 4096 + (wc * 64 + lrow) * 32 + lq * 8;

    auto issue = [&](int s, int p) {
        u16* base = smem + p * 8192 + wave * 512;
        const int k = s * 32;
        async16(gA0 + k, base);
        async16(gA1 + k, base + 2048);
        async16(gB0 + k, base + 4096);
        async16(gB1 + k, base + 4096 + 2048);
    };

    constexpr int NS = KLEN / 32;
    issue(0, 0);
#pragma unroll 2
    for (int s = 0; s < NS; ++s) {
        const int p = s & 1;
        if (s + 1 < NS) {
            issue(s + 1, p ^ 1);
            asm volatile("s_waitcnt vmcnt(4)" ::: "memory");
        } else {
            asm volatile("s_waitcnt vmcnt(0)" ::: "memory");
        }
        asm volatile("s_barrier" ::: "memory");  // current buf loaded (all waves)
        const u16* pa = smem + p * 8192 + aoff;
        const u16* pb = smem + p * 8192 + boff;
        shortx8 av[4], bv[4];
#pragma unroll
        for (int i = 0; i < 4; ++i) av[i] = *(const shortx8*)(pa + i * 512);
#pragma unroll
        for (int j = 0; j < 4; ++j) bv[j] = *(const shortx8*)(pb + j * 512);
#pragma unroll
        for (int i = 0; i < 4; ++i)
#pragma unroll
            for (int j = 0; j < 4; ++j)
                acc[i][j] = __builtin_amdgcn_mfma_f32_16x16x32_bf16(
                    av[i], bv[j], acc[i][j], 0, 0, 0);
        asm volatile("s_barrier" ::: "memory");  // reads done before buf reload
    }

    // epilogue — C/D mapping: col = lane&15, row = (lane>>4)*4 + reg
    u16* O;
    int cbase;
    if (EPI == 0) { O = (bn < 1024) ? O0 : O1; cbase = bn & 1023; }
    else          { O = blockIdx.z ? O1 : O0;  cbase = bn; }
#pragma unroll
    for (int i = 0; i < 4; ++i) {
        const int row0 = bm + wr * 64 + i * 16 + lq * 4;
#pragma unroll
        for (int j = 0; j < 4; ++j) {
            const int col = cbase + wc * 64 + j * 16 + lrow;
#pragma unroll
            for (int r = 0; r < 4; ++r)
                O[(size_t)(row0 + r) * 1024 + col] = f2bf(acc[i][j][r]);
        }
    }
}

// ---------------- K3: r = relu(sel(u + window(v) + biases, x)) in-place -----
__global__ __launch_bounds__(256)
void combine(u16* uv, const u16* __restrict__ v,
             const float* __restrict__ x, const float* __restrict__ qmask,
             const int* __restrict__ dia_len, const float* __restrict__ b_self,
             const float* __restrict__ b_msg)
{
    __shared__ u16 sv[32][1024];  // 64 KiB
    const int tid = threadIdx.x;
    const int b = blockIdx.y;
    const int t0 = blockIdx.x * 16;
    const int dlen = dia_len[b];
    const int c4 = tid * 4;

    unsigned spkmask = 0;
#pragma unroll 4
    for (int rr = 0; rr < 32; ++rr) {
        int row = t0 - 8 + rr;
        row = row < 0 ? 0 : (row > T_ - 1 ? T_ - 1 : row);
        const float* q = qmask + ((size_t)b * T_ + row) * 2;
        spkmask |= (q[1] > q[0] ? 1u : 0u) << rr;
        *(ushort4*)&sv[rr][c4] =
            *(const ushort4*)(v + ((size_t)b * T_ + row) * 1024 + c4);
    }
    __syncthreads();

    float4 bs;
    {
        float4 b1 = *(const float4*)(b_self + c4);
        float4 b2 = *(const float4*)(b_msg + c4);
        bs.x = b1.x + b2.x; bs.y = b1.y + b2.y;
        bs.z = b1.z + b2.z; bs.w = b1.w + b2.w;
    }

    for (int lt = 0; lt < 16; ++lt) {
        const int t = t0 + lt;
        const unsigned cs = (spkmask >> (lt + 8)) & 1u;
        float a0 = 0.f, a1 = 0.f, a2 = 0.f, a3 = 0.f;
        int cnt = 0;
#pragma unroll
        for (int o = 0; o < 17; ++o) {
            const int idx = t + o - 8;
            if (idx >= 0 && idx < dlen) {  // block-uniform branch
                const float w = (((spkmask >> (lt + o)) & 1u) == cs) ? 1.0f : 0.5f;
                ++cnt;
                ushort4 uu = *(const ushort4*)&sv[lt + o][c4];
                a0 += w * bf2f(uu.x); a1 += w * bf2f(uu.y);
                a2 += w * bf2f(uu.z); a3 += w * bf2f(uu.w);
            }
        }
        const float inv = 1.0f / (float)(cnt > 0 ? cnt : 1);
        const size_t rowg = (size_t)b * T_ + t;
        ushort4 u4 = *(const ushort4*)(uv + rowg * 1024 + c4);
        float4 xv = *(const float4*)(x + rowg * H_ + c4);
        const bool sel = (t < dlen);
        float h0 = bf2f(u4.x) + bs.x + a0 * inv;
        float h1 = bf2f(u4.y) + bs.y + a1 * inv;
        float h2 = bf2f(u4.z) + bs.z + a2 * inv;
        float h3 = bf2f(u4.w) + bs.w + a3 * inv;
        ushort4 outv;
        outv.x = f2bf(fmaxf(sel ? h0 : xv.x, 0.f));
        outv.y = f2bf(fmaxf(sel ? h1 : xv.y, 0.f));
        outv.z = f2bf(fmaxf(sel ? h2 : xv.z, 0.f));
        outv.w = f2bf(fmaxf(sel ? h3 : xv.w, 0.f));
        *(ushort4*)(uv + rowg * 1024 + c4) = outv;  // in-place over u
    }
}

// ---------------- K5: z = x + P0 + P1 + b_out; LayerNorm --------------------
__global__ __launch_bounds__(256)
void ln_final(const u16* __restrict__ P0, const u16* __restrict__ P1,
              const float* __restrict__ x, const float* __restrict__ b_out,
              const float* __restrict__ gamma, const float* __restrict__ beta,
              float* __restrict__ out)
{
    const int row = blockIdx.x;
    const int tid = threadIdx.x;
    const size_t base = (size_t)row * H_ + tid * 4;
    float4 xv = *(const float4*)(x + base);
    ushort4 p0 = *(const ushort4*)(P0 + base);
    ushort4 p1 = *(const ushort4*)(P1 + base);
    float4 bo = *(const float4*)(b_out + tid * 4);
    float4 v;
    v.x = xv.x + bf2f(p0.x) + bf2f(p1.x) + bo.x;
    v.y = xv.y + bf2f(p0.y) + bf2f(p1.y) + bo.y;
    v.z = xv.z + bf2f(p0.z) + bf2f(p1.z) + bo.z;
    v.w = xv.w + bf2f(p0.w) + bf2f(p1.w) + bo.w;
    float s = v.x + v.y + v.z + v.w;
    float q = v.x * v.x + v.y * v.y + v.z * v.z + v.w * v.w;
#pragma unroll
    for (int off = 32; off > 0; off >>= 1) {
        s += __shfl_down(s, off);
        q += __shfl_down(q, off);
    }
    __shared__ float ps[4], pq[4];
    const int wave = tid >> 6, lane = tid & 63;
    if (lane == 0) { ps[wave] = s; pq[wave] = q; }
    __syncthreads();
    const float S = ps[0] + ps[1] + ps[2] + ps[3];
    const float Q = pq[0] + pq[1] + pq[2] + pq[3];
    const float mean = S * (1.0f / 1024.0f);
    const float var = Q * (1.0f / 1024.0f) - mean * mean;
    const float inv = rsqrtf(var + 1e-5f);
    float4 g = *(const float4*)(gamma + tid * 4);
    float4 bt = *(const float4*)(beta + tid * 4);
    float4 o;
    o.x = g.x * (v.x - mean) * inv + bt.x;
    o.y = g.y * (v.y - mean) * inv + bt.y;
    o.z = g.z * (v.z - mean) * inv + bt.z;
    o.w = g.w * (v.w - mean) * inv + bt.w;
    *(float4*)(out + base) = o;
}

// ---------------- launcher ---------------------------------------------------
extern "C" void kernel_launch(void* const* d_in, const int* in_sizes, int n_in,
                              void* d_out, int out_size, void* d_ws, size_t ws_size,
                              hipStream_t stream)
{
    (void)in_sizes; (void)n_in; (void)out_size; (void)ws_size;
    const float* x       = (const float*)d_in[0];
    const float* qmask   = (const float*)d_in[1];
    const int*   dia_len = (const int*)d_in[2];
    const float* W_msg   = (const float*)d_in[5];
    const float* b_msg   = (const float*)d_in[6];
    const float* W_self  = (const float*)d_in[7];
    const float* b_self  = (const float*)d_in[8];
    const float* W_out   = (const float*)d_in[9];
    const float* b_out   = (const float*)d_in[10];
    const float* gamma   = (const float*)d_in[11];
    const float* beta    = (const float*)d_in[12];
    float* out = (float*)d_out;

    char* ws = (char*)d_ws;
    u16* region0 = (u16*)ws;                           // xbf -> P1
    u16* region1 = (u16*)(ws + (size_t)(16u << 20));   // u   -> r (in-place)
    u16* region2 = (u16*)(ws + (size_t)(32u << 20));   // v   -> P0
    u16* wt1     = (u16*)(ws + (size_t)(48u << 20));   // 4 MiB
    u16* wt_out  = (u16*)(ws + (size_t)(52u << 20));   // 2 MiB

    pack_x<<<dim3(8192), 256, 0, stream>>>(x, region0);
    transpose_pack<<<dim3(32, 32, 3), 256, 0, stream>>>(W_self, W_msg, W_out,
                                                        wt1, wt_out);
    gemm_bt<1024, 0><<<dim3(16, 64, 1), 256, 0, stream>>>(region0, wt1,
                                                          region1, region2);
    combine<<<dim3(64, 8), 256, 0, stream>>>(region1, region2, x, qmask,
                                             dia_len, b_self, b_msg);
    gemm_bt<512, 1><<<dim3(8, 64, 2), 256, 0, stream>>>(region1, wt_out,
                                                        region2, region0);
    ln_final<<<dim3(8192), 256, 0, stream>>>(region2, region0, x, b_out,
                                             gamma, beta, out);
}